// Round 1
// baseline (361.778 us; speedup 1.0000x reference)
//
#include <hip/hip_runtime.h>

#define T_STEPS 100
#define CHUNKS  25    // 100 floats = 25 float4 per element
#define TPB     64    // one wave per block -> no barriers at all
#define ELEMS   64    // elements per block (== TPB)
#define PGRID   1536  // persistent grid: 6 blocks/CU x 256 CU (LDS-capped occupancy)
// LDS: 64 elems * 25 float4 * 16B = 25600 B single buffer -> 6 blocks/CU

typedef const __attribute__((address_space(1))) unsigned int g_u32;
typedef __attribute__((address_space(3))) unsigned int l_u32;

// v2: persistent blocks + depth-1 cross-tile DMA prefetch + bit-packed spikes.
//
//  - tile t's 25 float4/lane are pulled LDS->VGPR up front (static indices,
//    ~100 VGPRs; LDS cap of 6 waves/CU means VGPRs are not the occupancy limit)
//  - tile t+1's global_load_lds DMA is issued into the SAME LDS buffer right
//    after lgkmcnt(0) confirms the reads, and flies under compute+stage-out
//  - spikes live as 100 bits in 4 u32 (exact: spike in {0,1}); no out-LDS
//    round trip, no second sync -> LDS is free for the prefetch
//  - stage-out: lane needs elem e=f/25's bits -> 4 ds_bpermute + selects,
//    expanded to exact 1.0f/0.0f; stores stay fully coalesced (1KB/instr)
//  - loop-end s_waitcnt vmcnt(25): queue (issue order) = [<=25 older stores,
//    25 prefetch DMAs, 25 fresh stores]; retiring to <=25 outstanding retires
//    the prefetch (in-order vmcnt), leaving only the fresh stores in flight.
//
// NUMERICS: float ops identical to the bit-exact v1 (contract off; op order
//   ((mem*TAU)+x)-w ; (BETA*w)+0.1*((A*m)+(B*s)); mem - spike*THRESH).
//   Bit-pack reuses the same (mem-0.5f)>0 compare; 1.0f/0.0f exact.
__global__ __launch_bounds__(TPB) void lif_kernel(const float* __restrict__ x,
                                                  float* __restrict__ out,
                                                  int nt) {
#pragma clang fp contract(off)
    __shared__ float4 tile[ELEMS * CHUNKS];   // 25.6 KB, single buffer

    const int lane = threadIdx.x;
    int ti = blockIdx.x;
    if (ti >= nt) return;

    // ---- prologue: DMA first tile, full drain once per block (~1-2k cyc) ----
    {
        const float4* __restrict__ xb = (const float4*)x + (size_t)ti * (ELEMS * CHUNKS);
#pragma unroll
        for (int k = 0; k < CHUNKS; ++k) {
            __builtin_amdgcn_global_load_lds(
                (g_u32*)(xb + k * TPB + lane), (l_u32*)&tile[k * TPB], 16, 0, 0);
        }
    }
    asm volatile("s_waitcnt vmcnt(0)" ::: "memory");
    __builtin_amdgcn_sched_barrier(0);

    while (true) {
        // ---- 1. LDS -> regs: own element's full series (static indices) ----
        float4 xv[CHUNKS];
#pragma unroll
        for (int c = 0; c < CHUNKS; ++c) xv[c] = tile[lane * CHUNKS + c];
        asm volatile("s_waitcnt lgkmcnt(0)" ::: "memory");  // reads done -> LDS reusable
        __builtin_amdgcn_sched_barrier(0);

        // ---- 2. prefetch next tile into the same buffer (flies under 3-4) --
        const int nxt = ti + PGRID;
        if (nxt < nt) {
            const float4* __restrict__ xb = (const float4*)x + (size_t)nxt * (ELEMS * CHUNKS);
#pragma unroll
            for (int k = 0; k < CHUNKS; ++k) {
                __builtin_amdgcn_global_load_lds(
                    (g_u32*)(xb + k * TPB + lane), (l_u32*)&tile[k * TPB], 16, 0, 0);
            }
        }

        // ---- 3. recurrence in registers; spikes packed into 100 bits -------
        unsigned b0 = 0, b1 = 0, b2 = 0, b3 = 0;
        float mem = 0.0f, w = 0.0f;
#pragma unroll
        for (int c = 0; c < CHUNKS; ++c) {
            float xs[4] = {xv[c].x, xv[c].y, xv[c].z, xv[c].w};
#pragma unroll
            for (int j = 0; j < 4; ++j) {
                mem = (mem * 0.5f + xs[j]) - w;                    // ((mem*TAU)+x)-w
                const bool fire = (mem - 0.5f) > 0.0f;             // ZIF forward
                const float spike = fire ? 1.0f : 0.0f;
                w = 0.9f * w + 0.1f * (0.5f * mem + 0.5f * spike); // numpy order
                mem = mem - spike * 0.5f;                          // soft reset
                const int t = c * 4 + j;                           // compile-time
                const unsigned bit = fire ? 1u : 0u;
                if (t < 32)      b0 |= bit << t;
                else if (t < 64) b1 |= bit << (t - 32);
                else if (t < 96) b2 |= bit << (t - 64);
                else             b3 |= bit << (t - 96);
            }
        }

        // ---- 4. stage-out: bpermute elem bits -> coalesced float4 stores ---
        float4* __restrict__ ob = (float4*)out + (size_t)ti * (ELEMS * CHUNKS);
#pragma unroll
        for (int k = 0; k < CHUNKS; ++k) {
            const int f = k * TPB + lane;       // tile-local float4 index
            const int e = f / 25;               // element (magic-mul, exact)
            const int c = f - e * 25;           // chunk within element
            const int a = e << 2;               // bpermute byte address
            const unsigned w0 = (unsigned)__builtin_amdgcn_ds_bpermute(a, (int)b0);
            const unsigned w1 = (unsigned)__builtin_amdgcn_ds_bpermute(a, (int)b1);
            const unsigned w2 = (unsigned)__builtin_amdgcn_ds_bpermute(a, (int)b2);
            const unsigned w3 = (unsigned)__builtin_amdgcn_ds_bpermute(a, (int)b3);
            const unsigned word = (c < 16) ? ((c < 8) ? w0 : w1)
                                           : ((c < 24) ? w2 : w3);
            const int sh = (c & 7) * 4;         // bits 4c..4c+3 of element e
            float4 s;
            s.x = ((word >> (sh + 0)) & 1u) ? 1.0f : 0.0f;
            s.y = ((word >> (sh + 1)) & 1u) ? 1.0f : 0.0f;
            s.z = ((word >> (sh + 2)) & 1u) ? 1.0f : 0.0f;
            s.w = ((word >> (sh + 3)) & 1u) ? 1.0f : 0.0f;
            ob[f] = s;
        }

        // ---- 5. advance; confirm prefetch landed (leave stores in flight) --
        ti = nxt;
        if (ti >= nt) break;
        asm volatile("s_waitcnt vmcnt(25)" ::: "memory");
        __builtin_amdgcn_sched_barrier(0);
    }
}

extern "C" void kernel_launch(void* const* d_in, const int* in_sizes, int n_in,
                              void* d_out, int out_size, void* d_ws, size_t ws_size,
                              hipStream_t stream) {
    const float* x = (const float*)d_in[0];
    float* out = (float*)d_out;
    int n_elem = in_sizes[0] / T_STEPS;       // 64*8192 = 524288
    int nt = n_elem / ELEMS;                  // 8192 tiles
    int grid = nt < PGRID ? nt : PGRID;       // persistent: 6 blocks/CU

    lif_kernel<<<grid, TPB, 0, stream>>>(x, out, nt);
}

// Round 2
// 358.830 us; speedup vs baseline: 1.0082x; 1.0082x over previous
//
#include <hip/hip_runtime.h>

#define T_STEPS 100
#define CHUNKS  25     // 100 floats = 25 float4 per element
#define TPB     256    // 4 waves per block
#define EPB     256    // elements per block (thread = element)
#define SLICES  5      // 5 time slices x 20 steps
#define SF4     5      // float4 per element per slice (20 floats)
#define WSLOT   (64 * SF4)   // 320 float4 per wave per slice buffer

typedef const __attribute__((address_space(1))) unsigned int g_u32;
typedef __attribute__((address_space(3))) unsigned int l_u32;

// v3: time-sliced LDS staging for occupancy (the v2 post-mortem lever).
//
//  - full-series staging costs 25.6 KB LDS/wave -> 6 waves/CU cap -> 2.4 TB/s.
//    Slicing 100 steps into 5 x 20 cuts LDS to 10 KB/wave: 2 x 20 KB buffers
//    per 256-thread block -> 4 blocks/CU = 16 waves/CU (LDS = 160 KB exactly).
//  - wave-self-contained: wave w's slice DMAs write LDS f4 slots [320w,320w+320)
//    and its own 64 threads read exactly that range (e=f/5 in [64w,64w+64)) ->
//    NO barriers anywhere; per-wave counted vmcnt double-buffer pipeline:
//      prologue: DMA slice0->buf0
//      iter s:   DMA slice s+1 -> buf^1 ; s_waitcnt vmcnt(5) (retires slice s)
//                ds_read own 5 f4 from buf ; 20 recurrence steps
//      iter 4:   vmcnt(0), no issue
//  - slice DMA global src is per-lane strided (80 B/elem at 400 B stride) --
//    allowed (only LDS dest must be linear); straddle lines re-hit by the next
//    slice within ~1 us -> L2/L3 absorb, HBM FETCH stays ~input size.
//  - output: v2's verified bit-pack (100 spike bits in 4 u32, exact since
//    spike in {0,1}) + ds_bpermute transpose -> 25 coalesced f4 stores/wave.
//
// NUMERICS: float ops identical to the bit-exact v1/v2 (contract off; op order
//   ((mem*TAU)+x)-w ; (BETA*w)+0.1*((A*m)+(B*s)); mem - spike*THRESH).
__global__ __launch_bounds__(TPB) void lif_kernel(const float* __restrict__ x,
                                                  float* __restrict__ out) {
#pragma clang fp contract(off)
    __shared__ float4 lds[2][EPB * SF4];   // 2 x 20 KB = 40960 B

    const int tid  = threadIdx.x;
    const int lane = tid & 63;
    const int w    = tid >> 6;

    // per-wave global base: 64 consecutive elements, 100 floats each
    const float* __restrict__ xw =
        x + ((size_t)blockIdx.x * EPB + (size_t)w * 64) * T_STEPS;

    // per-lane DMA src pointers for slice 0 (slice advance = +20 dwords)
    const float* src[SF4];
#pragma unroll
    for (int i = 0; i < SF4; ++i) {
        const int f = i * 64 + lane;       // wave-local float4 slot
        const int e = f / SF4;             // element within wave (magic-mul)
        const int c = f - e * SF4;         // float4 within slice
        src[i] = xw + e * T_STEPS + c * 4;
    }

    // ---- prologue: slice 0 -> buf 0 ----
#pragma unroll
    for (int i = 0; i < SF4; ++i)
        __builtin_amdgcn_global_load_lds(
            (g_u32*)src[i], (l_u32*)&lds[0][w * WSLOT + i * 64], 16, 0, 0);

    unsigned b0 = 0, b1 = 0, b2 = 0, b3 = 0;
    float mem = 0.0f, wreg = 0.0f;

#pragma unroll
    for (int s = 0; s < SLICES; ++s) {
        const int buf = s & 1;

        if (s + 1 < SLICES) {
            // issue next slice into the other buffer, then retire slice s
#pragma unroll
            for (int i = 0; i < SF4; ++i)
                __builtin_amdgcn_global_load_lds(
                    (g_u32*)(src[i] + (s + 1) * 4 * SF4),
                    (l_u32*)&lds[buf ^ 1][w * WSLOT + i * 64], 16, 0, 0);
            asm volatile("s_waitcnt vmcnt(5)" ::: "memory");
        } else {
            asm volatile("s_waitcnt vmcnt(0)" ::: "memory");
        }
        __builtin_amdgcn_sched_barrier(0);

        // own element's slice: 5 float4 (stride 80 B -> minimum-8 bank aliasing)
        float4 xv[SF4];
#pragma unroll
        for (int c = 0; c < SF4; ++c) xv[c] = lds[buf][tid * SF4 + c];

#pragma unroll
        for (int c = 0; c < SF4; ++c) {
            float xs[4] = {xv[c].x, xv[c].y, xv[c].z, xv[c].w};
#pragma unroll
            for (int j = 0; j < 4; ++j) {
                mem = (mem * 0.5f + xs[j]) - wreg;                     // ((mem*TAU)+x)-w
                const bool fire = (mem - 0.5f) > 0.0f;                 // ZIF forward
                const float spike = fire ? 1.0f : 0.0f;
                wreg = 0.9f * wreg + 0.1f * (0.5f * mem + 0.5f * spike); // numpy order
                mem = mem - spike * 0.5f;                              // soft reset
                const int t = s * 20 + c * 4 + j;                      // compile-time
                const unsigned bit = fire ? 1u : 0u;
                if (t < 32)      b0 |= bit << t;
                else if (t < 64) b1 |= bit << (t - 32);
                else if (t < 96) b2 |= bit << (t - 64);
                else             b3 |= bit << (t - 96);
            }
        }
    }

    // ---- stage-out: bpermute elem bits -> coalesced float4 stores (per wave) --
    float4* __restrict__ ow =
        (float4*)out + ((size_t)blockIdx.x * EPB + (size_t)w * 64) * CHUNKS;
#pragma unroll
    for (int k = 0; k < CHUNKS; ++k) {
        const int f = k * 64 + lane;        // wave-local output float4 index
        const int e = f / 25;               // source element (lane) within wave
        const int c = f - e * 25;           // chunk within element
        const int a = e << 2;               // bpermute byte address
        const unsigned w0 = (unsigned)__builtin_amdgcn_ds_bpermute(a, (int)b0);
        const unsigned w1 = (unsigned)__builtin_amdgcn_ds_bpermute(a, (int)b1);
        const unsigned w2 = (unsigned)__builtin_amdgcn_ds_bpermute(a, (int)b2);
        const unsigned w3 = (unsigned)__builtin_amdgcn_ds_bpermute(a, (int)b3);
        const unsigned word = (c < 16) ? ((c < 8) ? w0 : w1)
                                       : ((c < 24) ? w2 : w3);
        const int sh = (c & 7) * 4;         // bits 4c..4c+3 of element e
        float4 sv;
        sv.x = ((word >> (sh + 0)) & 1u) ? 1.0f : 0.0f;
        sv.y = ((word >> (sh + 1)) & 1u) ? 1.0f : 0.0f;
        sv.z = ((word >> (sh + 2)) & 1u) ? 1.0f : 0.0f;
        sv.w = ((word >> (sh + 3)) & 1u) ? 1.0f : 0.0f;
        ow[f] = sv;
    }
}

extern "C" void kernel_launch(void* const* d_in, const int* in_sizes, int n_in,
                              void* d_out, int out_size, void* d_ws, size_t ws_size,
                              hipStream_t stream) {
    const float* x = (const float*)d_in[0];
    float* out = (float*)d_out;
    int n_elem = in_sizes[0] / T_STEPS;   // 64*8192 = 524288
    int grid = n_elem / EPB;              // 2048 blocks, exact

    lif_kernel<<<grid, TPB, 0, stream>>>(x, out);
}